// Round 9
// baseline (587.619 us; speedup 1.0000x reference)
//
#include <hip/hip_runtime.h>

// Problem constants
#define Bb   64
#define Ss   257
#define Hh   12
#define HDd  64
#define Dd   768
#define Mv   16448        // B*S
#define M2   16512        // 129*128 (padded rows for 128-tiles)
#define NADH 512

typedef unsigned short u16;
typedef float  f32x4 __attribute__((ext_vector_type(4)));
typedef short  s16x8 __attribute__((ext_vector_type(8)));
typedef short  s16x4 __attribute__((ext_vector_type(4)));

__device__ __forceinline__ float bf2f(u16 u) {
  unsigned x = ((unsigned)u) << 16;
  return __builtin_bit_cast(float, x);
}
__device__ __forceinline__ u16 f2bf(float f) {
  unsigned x = __builtin_bit_cast(unsigned, f);
  x = x + 0x7fffu + ((x >> 16) & 1u);   // RNE
  return (u16)(x >> 16);
}
__device__ __forceinline__ void gload_lds16(const void* g, void* l) {
  __builtin_amdgcn_global_load_lds(
      (const __attribute__((address_space(1))) void*)g,
      (__attribute__((address_space(3))) void*)l, 16, 0, 0);
}

// ---------------------------------------------------------------------------
// hidden (Mv x 768 f32) -> bf16, zero-padded to M2 rows
__global__ void k_conv_hidden(const float* __restrict__ src, u16* __restrict__ dst) {
  size_t i4 = (size_t)blockIdx.x * 256 + threadIdx.x;
  size_t e = i4 * 4;
  size_t row = e / Dd;
  float4 v = make_float4(0.f, 0.f, 0.f, 0.f);
  if (row < Mv) v = *(const float4*)(src + e);
  ushort4 o;
  o.x = f2bf(v.x); o.y = f2bf(v.y); o.z = f2bf(v.z); o.w = f2bf(v.w);
  *(ushort4*)(dst + e) = o;
}

// W (K x N f32, [k][n]) -> Wt bf16 [n][k]
__global__ void k_tconv(const float* __restrict__ W, u16* __restrict__ Wt,
                        int K, int N) {
  __shared__ float tile[32][33];
  const int tx = threadIdx.x & 31, ty = threadIdx.x >> 5;  // 32 x 8
  const int n0 = blockIdx.x * 32, k0 = blockIdx.y * 32;
#pragma unroll
  for (int i = 0; i < 4; ++i)
    tile[ty + i*8][tx] = W[(size_t)(k0 + ty + i*8)*N + n0 + tx];
  __syncthreads();
#pragma unroll
  for (int i = 0; i < 4; ++i)
    Wt[(size_t)(n0 + ty + i*8)*K + k0 + tx] = f2bf(tile[tx][ty + i*8]);
}

// ---------------------------------------------------------------------------
// bf16 MFMA GEMM, m97-style: global_load_lds width-16 staging into LINEAR
// LDS (wave-uniform chunk base + per-lane global src), 128x128 tile, BK=32.
template<int OUTBF16>
__global__ __launch_bounds__(256) void k_gemm(
    const u16* __restrict__ A, const u16* __restrict__ Bt,
    const float* __restrict__ bias, void* __restrict__ Cout,
    int Mvalid, const float* lossbuf, float* lossout)
{
  const int N = Dd, K = Dd;
  __shared__ u16 As[128*32];
  __shared__ u16 Bs[128*32];
  const int tid = threadIdx.x;
  const int lane = tid & 63, wave = tid >> 6;
  const int m0 = blockIdx.x * 128, n0 = blockIdx.y * 128;

  if (lossout && blockIdx.x == 0 && blockIdx.y == 0 && tid == 0)
    lossout[0] = lossbuf[0];

  // staging geometry: tile = 8 KB = 8 chunks of 1 KB; chunk c: rows c*16..+15.
  // wave stages chunks 2w, 2w+1; lane l -> row c*16 + (l>>2), 16B-unit l&3.
  const int c0 = wave*2, c1 = wave*2 + 1;
  const int r0 = c0*16 + (lane >> 2), r1 = c1*16 + (lane >> 2);
  const int u8 = (lane & 3) * 8;
  const u16* gA0 = A  + (size_t)(m0 + r0)*K + u8;
  const u16* gA1 = A  + (size_t)(m0 + r1)*K + u8;
  const u16* gB0 = Bt + (size_t)(n0 + r0)*K + u8;
  const u16* gB1 = Bt + (size_t)(n0 + r1)*K + u8;
  u16* lA0 = As + c0*512;   // wave-uniform; HW adds lane*16B
  u16* lA1 = As + c1*512;
  u16* lB0 = Bs + c0*512;
  u16* lB1 = Bs + c1*512;

  f32x4 acc[4][4];
#pragma unroll
  for (int i = 0; i < 4; ++i)
#pragma unroll
    for (int j = 0; j < 4; ++j) acc[i][j] = f32x4{0.f, 0.f, 0.f, 0.f};

  const int wr = wave >> 1, wc = wave & 1;
  const int fr = lane & 15, g = lane >> 4;
  const s16x8* afp[4];
  const s16x8* bfp[4];
#pragma unroll
  for (int mi = 0; mi < 4; ++mi) {
    afp[mi] = (const s16x8*)(As + (wr*64 + mi*16 + fr)*32 + g*8);
    bfp[mi] = (const s16x8*)(Bs + (wc*64 + mi*16 + fr)*32 + g*8);
  }

  for (int kt = 0; kt < K/32; ++kt) {
    const int o = kt * 32;
    __syncthreads();
    gload_lds16(gA0 + o, lA0);
    gload_lds16(gA1 + o, lA1);
    gload_lds16(gB0 + o, lB0);
    gload_lds16(gB1 + o, lB1);
    __syncthreads();    // compiler drains vmcnt(0) before s_barrier
    s16x8 af[4], bf[4];
#pragma unroll
    for (int mi = 0; mi < 4; ++mi) af[mi] = afp[mi][0];
#pragma unroll
    for (int ni = 0; ni < 4; ++ni) bf[ni] = bfp[ni][0];
#pragma unroll
    for (int mi = 0; mi < 4; ++mi)
#pragma unroll
      for (int ni = 0; ni < 4; ++ni)
        acc[mi][ni] = __builtin_amdgcn_mfma_f32_16x16x32_bf16(af[mi], bf[ni], acc[mi][ni], 0, 0, 0);
  }

  // epilogue: C/D layout col = lane&15, row = (lane>>4)*4 + reg
#pragma unroll
  for (int ni = 0; ni < 4; ++ni) {
    const int col = n0 + wc*64 + ni*16 + fr;
    const float bv = bias[col];
#pragma unroll
    for (int mi = 0; mi < 4; ++mi) {
      const int rowb = m0 + wr*64 + mi*16 + g*4;
#pragma unroll
      for (int r = 0; r < 4; ++r) {
        const int row = rowb + r;
        if (row < Mvalid) {
          const float vv = acc[mi][ni][r] + bv;
          if (OUTBF16) ((u16*)Cout)[(size_t)row*N + col] = f2bf(vv);
          else         ((float*)Cout)[(size_t)row*N + col] = vv;
        }
      }
    }
  }
}

// ---------------------------------------------------------------------------
// Adversarial MLPs, half-(b,h) granularity: block = (bh, half). The _merge is
// block-local: merged rows half*32..+31 draw only on patch rows half*128..+127.
// Phase A: 128 tokens; phase B: 32 merged rows. LDS ~27KB -> 6 blocks/CU.
__global__ __launch_bounds__(256) void k_adv3(
    const u16* __restrict__ kbf,
    const u16* __restrict__ A1t, const float* __restrict__ a1,
    const float* __restrict__ A2, const float* __restrict__ a2,
    const u16* __restrict__ B1t, const float* __restrict__ b1,
    const float* __restrict__ B2, const float* __restrict__ b2,
    float* __restrict__ ent, float* __restrict__ lossacc)
{
  __shared__ u16  pb[1024*8];           // 128 rows x 64 bf16, swizzled 16B units
  __shared__ float ab1[512], aw2[512], bb1[512], bw2[512];
  __shared__ float p1s[128], l1s[128];
  __shared__ float s2part[4*32];
  __shared__ float p2s[32], l2s[32];
  __shared__ float red[256];

  const int tid = threadIdx.x;
  const int lane = tid & 63, wave = tid >> 6;
  const int fr = lane & 15, g = lane >> 4;
  const int bid = blockIdx.x;
  const int bh = bid >> 1, half = bid & 1;
  const int b = bh / Hh, h = bh % Hh;
  const size_t base = (size_t)b * Ss * Dd + (size_t)h * HDd;

  // stage 128 patch rows (tokens half*128..+127), bf16, swizzled 16B units
#pragma unroll
  for (int it = 0; it < 4; ++it) {
    const int u = it*256 + tid;
    const int row = u >> 3, c = u & 7;
    const s16x8 v = *(const s16x8*)(kbf + base + (size_t)(1 + half*128 + row)*Dd + c*8);
    *(s16x8*)(pb + (row*8 + (c ^ (row & 7)))*8) = v;
  }
  for (int i = tid; i < 512; i += 256) {
    ab1[i] = a1[i]; aw2[i] = A2[i]; bb1[i] = b1[i]; bw2[i] = B2[i];
  }
  __syncthreads();

  // ---- phase A: wave w owns local rows 32w..32w+31
  {
    s16x8 af[2][2];
#pragma unroll
    for (int mi = 0; mi < 2; ++mi)
#pragma unroll
      for (int kt = 0; kt < 2; ++kt) {
        const int row = wave*32 + mi*16 + fr;
        const int c = kt*4 + g;
        af[mi][kt] = *(const s16x8*)(pb + (row*8 + (c ^ (row & 7)))*8);
      }
    float sp[2][4];
#pragma unroll
    for (int mi = 0; mi < 2; ++mi)
#pragma unroll
      for (int r = 0; r < 4; ++r) sp[mi][r] = 0.f;

#pragma unroll 2
    for (int ni = 0; ni < 32; ++ni) {
      const int col = ni*16 + fr;
      f32x4 acc[2];
#pragma unroll
      for (int mi = 0; mi < 2; ++mi) acc[mi] = f32x4{0.f,0.f,0.f,0.f};
#pragma unroll
      for (int kt = 0; kt < 2; ++kt) {
        const s16x8 bfr = *(const s16x8*)(A1t + (size_t)col*64 + kt*32 + g*8);
#pragma unroll
        for (int mi = 0; mi < 2; ++mi)
          acc[mi] = __builtin_amdgcn_mfma_f32_16x16x32_bf16(af[mi][kt], bfr, acc[mi], 0, 0, 0);
      }
      const float c1v = ab1[col], w2 = aw2[col];
#pragma unroll
      for (int mi = 0; mi < 2; ++mi)
#pragma unroll
        for (int r = 0; r < 4; ++r)
          sp[mi][r] += fmaxf(acc[mi][r] + c1v, 0.f) * w2;
    }
#pragma unroll
    for (int mi = 0; mi < 2; ++mi)
#pragma unroll
      for (int r = 0; r < 4; ++r) {
        float v = sp[mi][r];
        v += __shfl_xor(v, 1); v += __shfl_xor(v, 2);
        v += __shfl_xor(v, 4); v += __shfl_xor(v, 8);
        if (fr == 0) {
          const int row = wave*32 + mi*16 + g*4 + r;
          const float z1 = v + a2[0];
          const float q = 1.f / (1.f + __expf(z1));
          p1s[row] = 1.f - q;
          l1s[row] = -__logf(fmaxf(q, 1e-10f));
        }
      }
  }

  // ---- phase B: 32 merged rows (local), wave w owns cols 128w..128w+127.
  // local prow(m,p) = (m>>3)*32 + (m&7)*2 + (p>>1)*16 + (p&1), m = local merged row
  {
    s16x8 am[2][8];
#pragma unroll
    for (int mi = 0; mi < 2; ++mi)
#pragma unroll
      for (int kt2 = 0; kt2 < 8; ++kt2) {
        const int m = mi*16 + fr;
        const int p = kt2 >> 1;
        const int prow = (m >> 3)*32 + (m & 7)*2 + (p >> 1)*16 + (p & 1);
        const int c = (kt2 & 1)*4 + g;
        am[mi][kt2] = *(const s16x8*)(pb + (prow*8 + (c ^ (prow & 7)))*8);
      }
    float sp2[2][4];
#pragma unroll
    for (int mi = 0; mi < 2; ++mi)
#pragma unroll
      for (int r = 0; r < 4; ++r) sp2[mi][r] = 0.f;

    for (int ni2 = 0; ni2 < 8; ++ni2) {
      const int col = wave*128 + ni2*16 + fr;
      f32x4 acc[2];
#pragma unroll
      for (int mi = 0; mi < 2; ++mi) acc[mi] = f32x4{0.f,0.f,0.f,0.f};
#pragma unroll
      for (int kt2 = 0; kt2 < 8; ++kt2) {
        const s16x8 bfr = *(const s16x8*)(B1t + (size_t)col*256 + kt2*32 + g*8);
#pragma unroll
        for (int mi = 0; mi < 2; ++mi)
          acc[mi] = __builtin_amdgcn_mfma_f32_16x16x32_bf16(am[mi][kt2], bfr, acc[mi], 0, 0, 0);
      }
      const float c1v = bb1[col], w2 = bw2[col];
#pragma unroll
      for (int mi = 0; mi < 2; ++mi)
#pragma unroll
        for (int r = 0; r < 4; ++r)
          sp2[mi][r] += fmaxf(acc[mi][r] + c1v, 0.f) * w2;
    }
#pragma unroll
    for (int mi = 0; mi < 2; ++mi)
#pragma unroll
      for (int r = 0; r < 4; ++r) {
        float v = sp2[mi][r];
        v += __shfl_xor(v, 1); v += __shfl_xor(v, 2);
        v += __shfl_xor(v, 4); v += __shfl_xor(v, 8);
        if (fr == 0) {
          const int m = mi*16 + g*4 + r;
          s2part[wave*32 + m] = v;
        }
      }
  }
  __syncthreads();
  if (tid < 32) {
    const float z2 = s2part[tid] + s2part[32 + tid] + s2part[64 + tid]
                   + s2part[96 + tid] + b2[0];
    const float q = 1.f / (1.f + __expf(z2));
    p2s[tid] = 1.f - q;
    l2s[tid] = -__logf(fmaxf(q, 1e-10f));
  }
  __syncthreads();

  // entropy for this half's 128 tokens
  float lc = 0.f;
  if (tid < 128) {
    const int tr = tid >> 4, cc2 = tid & 15;
    const float p2g = p2s[(tr >> 1)*8 + (cc2 >> 1)];
    const float p1v = p1s[tid];
    const float ad  = 0.525f*p1v + 0.475f*p2g;
    const float entv = -ad*__log2f(ad + 1e-10f) - (1.f - ad)*__log2f(1.f - ad + 1e-10f);
    ent[(size_t)bh*256 + half*128 + tid] = entv;
    lc = l1s[tid] * (1.f/196608.f);
    if (tid < 32) lc += l2s[tid] * (1.f/49152.f);
  }
  red[tid] = lc;
  __syncthreads();
  for (int s = 128; s > 0; s >>= 1) {
    if (tid < s) red[tid] += red[tid + s];
    __syncthreads();
  }
  if (tid == 0) atomicAdd(lossacc, red[0]);
}

// ---------------------------------------------------------------------------
// MFMA flash attention (passing, round-5): swapped QK^T, P in registers,
// V transposed in LDS (Vt[d][k], LD=292), plain ds_read_b64 B-fragments.
__global__ __launch_bounds__(256) void k_attn2(
    const u16* __restrict__ qb, const u16* __restrict__ kbf, const u16* __restrict__ vbf,
    const float* __restrict__ entp, u16* __restrict__ ctxb)
{
#define VLD 292
  __shared__ u16 Vt[64*VLD];   // 37376 B; Vt[d*VLD + k], k zero-padded to 288
  const int tid = threadIdx.x;
  const int lane = tid & 63, wave = tid >> 6;
  const int fr = lane & 15, g = lane >> 4;
  const int bh = blockIdx.x;
  const int b = bh / Hh, h = bh % Hh;
  const size_t base = (size_t)b * Ss * Dd + (size_t)h * HDd;

  // stage V transposed (zero k>=257)
  for (int c = tid; c < 2304; c += 256) {   // 288 k-rows x 8 d-chunks
    const int k = c >> 3, dc = c & 7;
    s16x8 v = s16x8{0,0,0,0,0,0,0,0};
    if (k < Ss) v = *(const s16x8*)(vbf + base + (size_t)k * Dd + dc * 8);
#pragma unroll
    for (int i = 0; i < 8; ++i) Vt[(dc*8 + i)*VLD + k] = (u16)v[i];
  }
  __syncthreads();

  for (int pi = 0; pi < 5; ++pi) {
    if (pi == 4 && wave != 0) break;
    const int rb = (pi == 4) ? 16 : pi*4 + wave;   // 17 row-blocks of 16 q-rows
    const int q0 = rb * 16;

    const u16* qr = qb + base + (size_t)(q0 + fr)*Dd + g*8;
    const s16x8 qf0 = *(const s16x8*)qr;
    const s16x8 qf1 = *(const s16x8*)(qr + 32);

    f32x4 acc[18];
#pragma unroll
    for (int ct = 0; ct < 18; ++ct) acc[ct] = f32x4{0.f,0.f,0.f,0.f};
#pragma unroll
    for (int ct = 0; ct < 18; ++ct) {
      const u16* kr = kbf + base + (size_t)(ct*16 + fr)*Dd + g*8;
      const s16x8 kf0 = *(const s16x8*)kr;
      const s16x8 kf1 = *(const s16x8*)(kr + 32);
      acc[ct] = __builtin_amdgcn_mfma_f32_16x16x32_bf16(kf0, qf0, acc[ct], 0, 0, 0);
      acc[ct] = __builtin_amdgcn_mfma_f32_16x16x32_bf16(kf1, qf1, acc[ct], 0, 0, 0);
    }

    // lane (fr,g) reg r holds scores[k = 16ct+4g+r][q-row = fr]
    float mx = -3e38f;
#pragma unroll
    for (int ct = 0; ct < 18; ++ct)
#pragma unroll
      for (int r = 0; r < 4; ++r) {
        const int k = ct*16 + g*4 + r;
        float s = acc[ct][r] * 0.125f;
        if (k >= Ss) s = -1e30f;
        acc[ct][r] = s;
        mx = fmaxf(mx, s);
      }
    mx = fmaxf(mx, __shfl_xor(mx, 16));
    mx = fmaxf(mx, __shfl_xor(mx, 32));
    float sum = 0.f;
#pragma unroll
    for (int ct = 0; ct < 18; ++ct)
#pragma unroll
      for (int r = 0; r < 4; ++r) {
        const float p = __expf(acc[ct][r] - mx);
        acc[ct][r] = p;
        sum += p;
      }
    sum += __shfl_xor(sum, 16);
    sum += __shfl_xor(sum, 32);
    const float inv = 1.f / sum;

    // entropy reweighting of q-row 0 (post-softmax, no renorm)
    if (rb == 0 && fr == 0) {
#pragma unroll
      for (int ct = 0; ct < 17; ++ct)
#pragma unroll
        for (int r = 0; r < 4; ++r) {
          const int k = ct*16 + g*4 + r;
          if (k > 0 && k < Ss) acc[ct][r] *= entp[(size_t)bh*256 + k - 1];
        }
    }

    unsigned pk[18][2];
#pragma unroll
    for (int ct = 0; ct < 18; ++ct) {
      pk[ct][0] = (unsigned)f2bf(acc[ct][0]*inv) | ((unsigned)f2bf(acc[ct][1]*inv) << 16);
      pk[ct][1] = (unsigned)f2bf(acc[ct][2]*inv) | ((unsigned)f2bf(acc[ct][3]*inv) << 16);
    }

    f32x4 o[4];
#pragma unroll
    for (int dt = 0; dt < 4; ++dt) o[dt] = f32x4{0.f,0.f,0.f,0.f};

#pragma unroll
    for (int kt = 0; kt < 9; ++kt) {
      const unsigned au0 = pk[2*kt][0], au1 = pk[2*kt][1];
      const unsigned au2 = pk[2*kt+1][0], au3 = pk[2*kt+1][1];
      s16x8 af;
      af[0] = (short)(au0 & 0xffff); af[1] = (short)(au0 >> 16);
      af[2] = (short)(au1 & 0xffff); af[3] = (short)(au1 >> 16);
      af[4] = (short)(au2 & 0xffff); af[5] = (short)(au2 >> 16);
      af[6] = (short)(au3 & 0xffff); af[7] = (short)(au3 >> 16);
#pragma unroll
      for (int dt = 0; dt < 4; ++dt) {
        const int hw = (dt*16 + fr)*VLD + kt*32 + g*4;
        const s16x4 lo = *(const s16x4*)(Vt + hw);
        const s16x4 hi = *(const s16x4*)(Vt + hw + 16);
        const s16x8 bf = {lo[0],lo[1],lo[2],lo[3],hi[0],hi[1],hi[2],hi[3]};
        o[dt] = __builtin_amdgcn_mfma_f32_16x16x32_bf16(af, bf, o[dt], 0, 0, 0);
      }
    }

#pragma unroll
    for (int r = 0; r < 4; ++r) {
      const int row = q0 + g*4 + r;
      if (row < Ss) {
#pragma unroll
        for (int dt = 0; dt < 4; ++dt)
          ctxb[base + (size_t)row*Dd + dt*16 + fr] = f2bf(o[dt][r]);
      }
    }
  }
#undef VLD
}

// ---------------------------------------------------------------------------
extern "C" void kernel_launch(void* const* d_in, const int* in_sizes, int n_in,
                              void* d_out, int out_size, void* d_ws, size_t ws_size,
                              hipStream_t stream) {
  const float* hid = (const float*)d_in[0];
  const float* Wq  = (const float*)d_in[1];
  const float* bq  = (const float*)d_in[2];
  const float* Wk  = (const float*)d_in[3];
  const float* bk  = (const float*)d_in[4];
  const float* Wv  = (const float*)d_in[5];
  const float* bv  = (const float*)d_in[6];
  const float* Wo  = (const float*)d_in[7];
  const float* bo  = (const float*)d_in[8];
  const float* A1  = (const float*)d_in[9];
  const float* a1  = (const float*)d_in[10];
  const float* A2  = (const float*)d_in[11];
  const float* a2  = (const float*)d_in[12];
  const float* B1  = (const float*)d_in[13];
  const float* b1  = (const float*)d_in[14];
  const float* B2  = (const float*)d_in[15];
  const float* b2  = (const float*)d_in[16];

  char* p = (char*)d_ws;
  size_t off = 0;
  auto alloc = [&](size_t bytes) -> void* {
    void* r = p + off; off += (bytes + 255) & ~(size_t)255; return r;
  };
  u16*   hb   = (u16*)  alloc((size_t)M2*Dd*2);
  u16*   wqt  = (u16*)  alloc((size_t)Dd*Dd*2);
  u16*   wkt  = (u16*)  alloc((size_t)Dd*Dd*2);
  u16*   wvt  = (u16*)  alloc((size_t)Dd*Dd*2);
  u16*   wot  = (u16*)  alloc((size_t)Dd*Dd*2);
  u16*   qbb  = (u16*)  alloc((size_t)M2*Dd*2);
  u16*   kb   = (u16*)  alloc((size_t)M2*Dd*2);
  u16*   vb   = (u16*)  alloc((size_t)M2*Dd*2);
  u16*   ctxb = (u16*)  alloc((size_t)M2*Dd*2);
  float* entw = (float*)alloc((size_t)Bb*Hh*256*4);
  float* lossw = (float*)alloc(256);
  u16*   a1tb = (u16*)  alloc((size_t)NADH*HDd*2);      // A1t [512][64] bf16
  u16*   b1tb = (u16*)  alloc((size_t)NADH*4*HDd*2);    // B1t [512][256] bf16

  hipMemsetAsync(lossw, 0, 4, stream);
  k_conv_hidden<<<dim3((M2*Dd/4)/256), 256, 0, stream>>>(hid, hb);
  dim3 tg(24, 24);
  k_tconv<<<tg, 256, 0, stream>>>(Wq, wqt, Dd, Dd);
  k_tconv<<<tg, 256, 0, stream>>>(Wk, wkt, Dd, Dd);
  k_tconv<<<tg, 256, 0, stream>>>(Wv, wvt, Dd, Dd);
  k_tconv<<<tg, 256, 0, stream>>>(Wo, wot, Dd, Dd);
  k_tconv<<<dim3(16, 2), 256, 0, stream>>>(A1, a1tb, HDd, NADH);
  k_tconv<<<dim3(16, 8), 256, 0, stream>>>(B1, b1tb, 4*HDd, NADH);
  dim3 gg(129, 6);
  k_gemm<1><<<gg, 256, 0, stream>>>(hb, wqt, bq, qbb, Mv, nullptr, nullptr);
  k_gemm<1><<<gg, 256, 0, stream>>>(hb, wkt, bk, kb, Mv, nullptr, nullptr);
  k_gemm<1><<<gg, 256, 0, stream>>>(hb, wvt, bv, vb, Mv, nullptr, nullptr);
  k_adv3<<<Bb*Hh*2, 256, 0, stream>>>(kb, a1tb, a1, A2, a2, b1tb, b1, B2, b2, entw, lossw);
  k_attn2<<<Bb*Hh, 256, 0, stream>>>(qbb, kb, vb, entw, ctxb);
  k_gemm<0><<<gg, 256, 0, stream>>>(ctxb, wot, bo, (float*)d_out, Mv,
                                    lossw, ((float*)d_out) + (size_t)Mv*Dd);
}